// Round 6
// baseline (245.670 us; speedup 1.0000x reference)
//
#include <hip/hip_runtime.h>

// GCN block: h1 = ReLU(Agg(x@W1)+b1); h2 = ReLU(Agg(h1@W2)+b2); out = BN(h2)
// R21: quarter-row gathers. Row read as 16 lanes x 16B (dwordx4) instead of
// 32 lanes x 8B; the wave's 4 16-lane groups own quarters of the slot list
// (bucket: slot s -> quarter s&3, idx s>>2; sentinel-padded per quarter).
// One 8-load asm block now covers 32 edges/wait (99.99% of nodes in ONE
// latency step, killing the 16% second-wait tail) and doubles in-flight
// cache lines per wave (64 -> 128). No launch_bounds force (R19 spill
// lesson): 32 dest VGPRs live across the wait, expect ~80-96 VGPR.

#define D 128
#define CAP 96   // max in-degree capacity; E/N=12 mean, Poisson tail << 96

typedef __attribute__((ext_vector_type(8))) short bf16x8;
typedef __attribute__((ext_vector_type(4))) float f32x4;
typedef __attribute__((ext_vector_type(8))) float f32x8;
typedef __attribute__((ext_vector_type(4))) unsigned u32x4;

__device__ inline float2 bf2x2(unsigned u) {
    float2 r;
    r.x = __uint_as_float(u << 16);
    r.y = __uint_as_float(u & 0xffff0000u);
    return r;
}
__device__ inline unsigned short f2bf(float f) {
    unsigned u = __float_as_uint(f);
    u += 0x7fffu + ((u >> 16) & 1u);   // round-to-nearest-even
    return (unsigned short)(u >> 16);
}
__device__ inline unsigned pack2(float a, float b) {
    return (unsigned)f2bf(a) | ((unsigned)f2bf(b) << 16);
}

// ------- fused histogram+fill: one atomic per edge; + W transpose-convert -------
// Quarter-split bucket layout: slot s -> quarter s&3, index s>>2.
__global__ void k_histfill(const int* __restrict__ row, const int* __restrict__ col,
                           int* __restrict__ cnt, int* __restrict__ bucket, int E,
                           const float* __restrict__ W1, const float* __restrict__ W2,
                           unsigned short* __restrict__ Wt1,
                           unsigned short* __restrict__ Wt2) {
    int e = blockIdx.x * blockDim.x + threadIdx.x;
    if (e < E) {
        int c = col[e];
        int slot = atomicAdd(&cnt[c], 1);
        if (slot < CAP)
            bucket[(size_t)c * CAP + (slot & 3) * (CAP / 4) + (slot >> 2)] = row[e];
    }
    if (blockIdx.x < D) {
        int k = blockIdx.x;
        int t = threadIdx.x;
        if (t < D) Wt1[t * D + k] = f2bf(W1[k * D + t]);
        else       Wt2[(t - D) * D + k] = f2bf(W2[k * D + (t - D)]);
    }
}

// ------ 16-wave GEMM compute: wave w -> m-tile w>>1, n-half w&1 (4 n-tiles) ------
__device__ inline void gemm_compute16(const unsigned short* Xs, const unsigned short* Ws,
                                      const int* __restrict__ cnt,
                                      unsigned short* __restrict__ out, int n, int row0) {
    int tid = threadIdx.x;
    int w = tid >> 6;          // 0..15
    int wm = w >> 1;           // m-tile 0..7
    int wn = w & 1;            // n-half 0..1
    int lane = tid & 63;
    int m16 = lane & 15;
    int quad = lane >> 4;

    f32x4 acc[4];
#pragma unroll
    for (int u = 0; u < 4; u++) acc[u] = (f32x4){0.f, 0.f, 0.f, 0.f};

#pragma unroll
    for (int kc = 0; kc < 4; kc++) {
        bf16x8 a = *(const bf16x8*)&Xs[(wm * 16 + m16) * 136 + kc * 32 + quad * 8];
        bf16x8 b[4];
#pragma unroll
        for (int u = 0; u < 4; u++)
            b[u] = *(const bf16x8*)&Ws[((wn * 4 + u) * 16 + m16) * 136 + kc * 32 + quad * 8];
#pragma unroll
        for (int u = 0; u < 4; u++)
            acc[u] = __builtin_amdgcn_mfma_f32_16x16x32_bf16(a, b[u], acc[u], 0, 0, 0);
    }

    int rbase = row0 + wm * 16 + quad * 4;
#pragma unroll
    for (int i = 0; i < 4; i++) {
        int r = rbase + i;
        if (r < n) {
            float sc = rsqrtf((float)cnt[r] + 1.0f);
#pragma unroll
            for (int u = 0; u < 4; u++)
                out[(size_t)r * D + (wn * 4 + u) * 16 + m16] = f2bf(acc[u][i] * sc);
        }
    }
}

// -- GEMM1 (1024 thr, 16 waves): out[r] = bf16((X @ W)[r] * rsqrt(cnt[r]+1)) --
// Also sentinel-pads the bucket (8 slots past each quarter's count -> n).
__global__ __launch_bounds__(1024) void k_gemm1(
        const float* __restrict__ Xf, const unsigned short* __restrict__ Wt,
        const int* __restrict__ cnt, int* __restrict__ bucket,
        unsigned short* __restrict__ out, int n) {
    __shared__ unsigned short Xs[128 * 136];   // +8 pad: 2-way banks (free)
    __shared__ unsigned short Ws[128 * 136];
    int tid = threadIdx.x;
    int row0 = blockIdx.x * 128;

#pragma unroll
    for (int i = 0; i < 2; i++) {
        int c = tid + 1024 * i;
        int r = c >> 4;
        int kc = (c & 15) * 8;
        float4 va = {0.f, 0.f, 0.f, 0.f}, vb = {0.f, 0.f, 0.f, 0.f};
        if (row0 + r < n) {
            va = *(const float4*)&Xf[(size_t)(row0 + r) * D + kc];
            vb = *(const float4*)&Xf[(size_t)(row0 + r) * D + kc + 4];
        }
        ushort4 o0, o1;
        o0.x = f2bf(va.x); o0.y = f2bf(va.y); o0.z = f2bf(va.z); o0.w = f2bf(va.w);
        o1.x = f2bf(vb.x); o1.y = f2bf(vb.y); o1.z = f2bf(vb.z); o1.w = f2bf(vb.w);
        *(ushort4*)&Xs[r * 136 + kc] = o0;
        *(ushort4*)&Xs[r * 136 + kc + 4] = o1;
    }
#pragma unroll
    for (int i = 0; i < 2; i++) {
        int c = tid + 1024 * i;
        int r = c >> 4;
        int kc = (c & 15) * 8;
        uint4 v = *(const uint4*)&Wt[r * D + kc];
        *(uint4*)&Ws[r * 136 + kc] = v;
    }
    // sentinel pad: 128 nodes x 4 quarters x 8 slots = 4096 writes, 4/thread
#pragma unroll
    for (int q = 0; q < 4; q++) {
        int s = tid + 1024 * q;
        int nl = s >> 5, rest = s & 31;
        int qr = rest >> 3, kk = rest & 7;
        int node = row0 + nl;
        if (node < n) {
            int ch = (min(cnt[node], CAP) - qr + 3) >> 2;
            int j = ch + kk;
            if (j < CAP / 4)
                bucket[(size_t)node * CAP + qr * (CAP / 4) + j] = n;
        }
    }
    __syncthreads();
    gemm_compute16(Xs, Ws, cnt, out, n, row0);
}

// ---- forced-MLP gather: 8 concurrent 16B row-quarter gathers (issue only) ----
struct G8Q { u32x4 a, b, c, d, e, f, g, h; };

__device__ inline G8Q issue8q(const uint2* __restrict__ hs2,
                              unsigned o0, unsigned o1, unsigned o2, unsigned o3,
                              unsigned o4, unsigned o5, unsigned o6, unsigned o7) {
    G8Q r;
    asm volatile(
        "global_load_dwordx4 %0, %8, %16\n\t"
        "global_load_dwordx4 %1, %9, %16\n\t"
        "global_load_dwordx4 %2, %10, %16\n\t"
        "global_load_dwordx4 %3, %11, %16\n\t"
        "global_load_dwordx4 %4, %12, %16\n\t"
        "global_load_dwordx4 %5, %13, %16\n\t"
        "global_load_dwordx4 %6, %14, %16\n\t"
        "global_load_dwordx4 %7, %15, %16"
        : "=&v"(r.a), "=&v"(r.b), "=&v"(r.c), "=&v"(r.d),
          "=&v"(r.e), "=&v"(r.f), "=&v"(r.g), "=&v"(r.h)
        : "v"(o0), "v"(o1), "v"(o2), "v"(o3),
          "v"(o4), "v"(o5), "v"(o6), "v"(o7),
          "s"(hs2));
    return r;
}

__device__ inline void wait_vm0() {
    asm volatile("s_waitcnt vmcnt(0)" ::: "memory");
    __builtin_amdgcn_sched_barrier(0);   // keep consumers below (rule: hipcc
                                         // hoists reg-only ops past asm waits)
}

__device__ inline void cons4(const u32x4& u, f32x8& A) {
    float2 x;
    x = bf2x2(u[0]); A[0] += x.x; A[1] += x.y;
    x = bf2x2(u[1]); A[2] += x.x; A[3] += x.y;
    x = bf2x2(u[2]); A[4] += x.x; A[5] += x.y;
    x = bf2x2(u[3]); A[6] += x.x; A[7] += x.y;
}
__device__ inline void consume8q(const G8Q& g, f32x8& A) {
    cons4(g.a, A); cons4(g.b, A); cons4(g.c, A); cons4(g.d, A);
    cons4(g.e, A); cons4(g.f, A); cons4(g.g, A); cons4(g.h, A);
}

#define QOFF(s) ((((unsigned)(s)) << 8) + l16b)

// ---- device agg for one node; group-0 lanes get 8 features (bias+ReLU) ----
// Bucket quarter-sentinel-padded (slot n -> zeroed row): no masking anywhere.
// Tail loop bound uses group-0's count (max, wave-uniform) — other groups
// read sentinel slots, which is safe and cheap (L1-hot zero row).
__device__ inline void agg_node_q(const uint2* __restrict__ hs2,
                                  const int* __restrict__ cp, int dcnt,
                                  int4 sa, int4 sb,
                                  const float* __restrict__ bias,
                                  int node, int grp, int l16, unsigned l16b,
                                  f32x8& O) {
    u32x4 su = *(const u32x4*)((const char*)hs2 + ((size_t)node << 8) + l16b);
    G8Q g = issue8q(hs2, QOFF(sa.x), QOFF(sa.y), QOFF(sa.z), QOFF(sa.w),
                         QOFF(sb.x), QOFF(sb.y), QOFF(sb.z), QOFF(sb.w));
    wait_vm0();
    f32x8 A = {0.f, 0.f, 0.f, 0.f, 0.f, 0.f, 0.f, 0.f};
    consume8q(g, A);
    int ch0 = (min(dcnt, CAP) + 3) >> 2;   // group-0 count (uniform max)
#pragma unroll 1
    for (int k = 8; k < ch0; k += 8) {     // deg > 32 only: ~0% of nodes
        int4 xa = *(const int4*)(cp + k);
        int4 xb = *(const int4*)(cp + k + 4);
        G8Q t = issue8q(hs2, QOFF(xa.x), QOFF(xa.y), QOFF(xa.z), QOFF(xa.w),
                             QOFF(xb.x), QOFF(xb.y), QOFF(xb.z), QOFF(xb.w));
        wait_vm0();
        consume8q(t, A);
    }
    if (grp == 0) {   // self term (pre-scaled row), counted once
        float2 x;
        x = bf2x2(su[0]); A[0] += x.x; A[1] += x.y;
        x = bf2x2(su[1]); A[2] += x.x; A[3] += x.y;
        x = bf2x2(su[2]); A[4] += x.x; A[5] += x.y;
        x = bf2x2(su[3]); A[6] += x.x; A[7] += x.y;
    }
#pragma unroll
    for (int j = 0; j < 8; j++) {          // all 64 lanes: cross-group reduce
        float v = A[j];
        v += __shfl_xor(v, 16);
        v += __shfl_xor(v, 32);
        A[j] = v;
    }
    O = (f32x8){0.f, 0.f, 0.f, 0.f, 0.f, 0.f, 0.f, 0.f};
    if (grp == 0) {
        float dn = rsqrtf((float)dcnt + 1.0f);
        float4 b0 = *(const float4*)&bias[8 * l16];
        float4 b1 = *(const float4*)&bias[8 * l16 + 4];
        O[0] = fmaxf(dn * A[0] + b0.x, 0.f);
        O[1] = fmaxf(dn * A[1] + b0.y, 0.f);
        O[2] = fmaxf(dn * A[2] + b0.z, 0.f);
        O[3] = fmaxf(dn * A[3] + b0.w, 0.f);
        O[4] = fmaxf(dn * A[4] + b1.x, 0.f);
        O[5] = fmaxf(dn * A[5] + b1.y, 0.f);
        O[6] = fmaxf(dn * A[6] + b1.z, 0.f);
        O[7] = fmaxf(dn * A[7] + b1.w, 0.f);
    }
}

// ------- FUSED agg1+GEMM2 (1024 thr): phase A — 16 waves aggregate 8 nodes -------
// ------- each into Xs (LDS); phase B — 16-wave MFMA GEMM -> g2b (distinct). -----
__global__ __launch_bounds__(1024) void k_agg_gemm(
        const uint2* __restrict__ hs2, const int* __restrict__ bucket,
        const int* __restrict__ cnt, const float* __restrict__ bias,
        const unsigned short* __restrict__ Wt, unsigned short* __restrict__ out,
        int n) {
    __shared__ unsigned short Xs[128 * 136];
    __shared__ unsigned short Ws[128 * 136];
    int tid = threadIdx.x;
    int row0 = blockIdx.x * 128;
    int w = tid >> 6;          // 0..15
    int lane = tid & 63;
    int grp = lane >> 4;       // 0..3 (row-quarter group)
    int l16 = lane & 15;
    unsigned l16b = (unsigned)l16 * 16u;
    const int* gb = bucket + grp * (CAP / 4);

    // phase A: wave w aggregates nodes row0 + w*8 + j, j=0..7 (slot/cnt pipelined)
    int nb = row0 + w * 8;
    const int* cp = gb + (size_t)min(nb, n - 1) * CAP;
    int4 sa = *(const int4*)cp;
    int4 sb = *(const int4*)(cp + 4);
    int dcnt = cnt[min(nb, n - 1)];
#pragma unroll 1
    for (int j = 0; j < 8; j++) {
        int node = nb + j;
        // prefetch next node's slots + cnt (issued before the gather wait)
        int nn = min(node + 1, n - 1);
        const int* cpn = gb + (size_t)nn * CAP;
        int4 sa_n = *(const int4*)cpn;
        int4 sb_n = *(const int4*)(cpn + 4);
        int dc_n = cnt[nn];
        f32x8 O = {0.f, 0.f, 0.f, 0.f, 0.f, 0.f, 0.f, 0.f};
        if (node < n)
            agg_node_q(hs2, cp, dcnt, sa, sb, bias, node, grp, l16, l16b, O);
        if (grp == 0) {
            uint4 o;
            o.x = pack2(O[0], O[1]); o.y = pack2(O[2], O[3]);
            o.z = pack2(O[4], O[5]); o.w = pack2(O[6], O[7]);
            *(uint4*)&Xs[(w * 8 + j) * 136 + l16 * 8] = o;
        }
        cp = cpn; sa = sa_n; sb = sb_n; dcnt = dc_n;
    }
    // stage Ws
#pragma unroll
    for (int i = 0; i < 2; i++) {
        int c = tid + 1024 * i;
        int r = c >> 4;
        int kc = (c & 15) * 8;
        uint4 v = *(const uint4*)&Wt[r * D + kc];
        *(uint4*)&Ws[r * 136 + kc] = v;
    }
    __syncthreads();

    // phase B: GEMM on the LDS-resident h1 tile
    gemm_compute16(Xs, Ws, cnt, out, n, row0);
}

// ---- FUSED agg2 + BN-stats (1024 thr, 512 blocks, grid-stride over nodes) ----
__global__ __launch_bounds__(1024) void k_agg_stats(
        const uint2* __restrict__ hs2, const int* __restrict__ bucket,
        const int* __restrict__ cnt, const float* __restrict__ bias,
        unsigned short* __restrict__ h2, float* __restrict__ S, int N) {
    int tid = threadIdx.x;
    int w = tid >> 6;
    int lane = tid & 63;
    int grp = lane >> 4;
    int l16 = lane & 15;
    unsigned l16b = (unsigned)l16 * 16u;
    const int* gb = bucket + grp * (CAP / 4);

    f32x8 st = {0.f, 0.f, 0.f, 0.f, 0.f, 0.f, 0.f, 0.f};
    f32x8 sq = {0.f, 0.f, 0.f, 0.f, 0.f, 0.f, 0.f, 0.f};

    int stride = gridDim.x * 16;
    int node = blockIdx.x * 16 + w;
    int4 sa = {0, 0, 0, 0}, sb = {0, 0, 0, 0};
    int dcnt = 0;
    if (node < N) {
        const int* cp0 = gb + (size_t)node * CAP;
        sa = *(const int4*)cp0;
        sb = *(const int4*)(cp0 + 4);
        dcnt = cnt[node];
    }
#pragma unroll 1
    for (; node < N; node += stride) {
        // prefetch next grid-stride node's slots + cnt (overlaps the wait)
        int nn = min(node + stride, N - 1);
        const int* cpn = gb + (size_t)nn * CAP;
        int4 sa_n = *(const int4*)cpn;
        int4 sb_n = *(const int4*)(cpn + 4);
        int dc_n = cnt[nn];
        const int* cp = gb + (size_t)node * CAP;
        f32x8 O;
        agg_node_q(hs2, cp, dcnt, sa, sb, bias, node, grp, l16, l16b, O);
        if (grp == 0) {
            uint4 o;
            o.x = pack2(O[0], O[1]); o.y = pack2(O[2], O[3]);
            o.z = pack2(O[4], O[5]); o.w = pack2(O[6], O[7]);
            *(uint4*)&h2[(size_t)node * D + l16 * 8] = o;
#pragma unroll
            for (int j = 0; j < 8; j++) { st[j] += O[j]; sq[j] += O[j] * O[j]; }
        }
        sa = sa_n; sb = sb_n; dcnt = dc_n;
    }

    __shared__ float sm[16][16][16];
    if (grp == 0) {
#pragma unroll
        for (int j = 0; j < 8; j++) {
            sm[w][l16][j] = st[j];
            sm[w][l16][8 + j] = sq[j];
        }
    }
    __syncthreads();
    if (tid < D) {
        int f = tid;
        float s = 0.f, q = 0.f;
#pragma unroll
        for (int ww = 0; ww < 16; ww++) {
            s += sm[ww][f >> 3][f & 7];
            q += sm[ww][f >> 3][8 + (f & 7)];
        }
        atomicAdd(&S[f * 16], s);
        atomicAdd(&S[4096 + f * 16], q);
    }
}

// ---------------- BN normalize: bf16 h2 -> f32 out ----------------
__global__ void k_bn(const unsigned* __restrict__ z2, const float* __restrict__ S,
                     const float* __restrict__ gamma, const float* __restrict__ beta,
                     float* __restrict__ out, int N) {
    int i = blockIdx.x * blockDim.x + threadIdx.x;   // uint4 index (8 features)
    int total = N * (D / 8);
    if (i >= total) return;
    int c8 = (i & (D / 8 - 1)) * 8;
    uint4 u = *(const uint4*)&z2[(size_t)i * 4];
    float v[8];
    float2 t;
    t = bf2x2(u.x); v[0] = t.x; v[1] = t.y;
    t = bf2x2(u.y); v[2] = t.x; v[3] = t.y;
    t = bf2x2(u.z); v[4] = t.x; v[5] = t.y;
    t = bf2x2(u.w); v[6] = t.x; v[7] = t.y;
    float invN = 1.0f / (float)N;
    float4 o0, o1;
#pragma unroll
    for (int j = 0; j < 8; j++) {
        float s = S[(c8 + j) * 16];
        float s2 = S[4096 + (c8 + j) * 16];
        float mu = s * invN;
        float iv = rsqrtf(fmaxf(s2 * invN - mu * mu, 0.f) + 1e-5f);
        float val = gamma[c8 + j] * (v[j] - mu) * iv + beta[c8 + j];
        if (j < 4) (&o0.x)[j] = val; else (&o1.x)[j - 4] = val;
    }
    size_t base = (size_t)i * 8;
    *(float4*)&out[base] = o0;
    *(float4*)&out[base + 4] = o1;
}

static inline size_t align_up(size_t x) { return (x + 1023) & ~(size_t)1023; }

extern "C" void kernel_launch(void* const* d_in, const int* in_sizes, int n_in,
                              void* d_out, int out_size, void* d_ws, size_t ws_size,
                              hipStream_t stream) {
    const float* x     = (const float*)d_in[0];
    const int*   ei    = (const int*)d_in[1];
    const float* W1    = (const float*)d_in[2];
    const float* b1    = (const float*)d_in[3];
    const float* W2    = (const float*)d_in[4];
    const float* b2    = (const float*)d_in[5];
    const float* gamma = (const float*)d_in[6];
    const float* beta  = (const float*)d_in[7];

    int N = in_sizes[0] / D;
    int E = in_sizes[1] / 2;
    const int* row = ei;
    const int* col = ei + E;

    char* p = (char*)d_ws;
    int* cnt    = (int*)p;                 // cnt[N] ++ S[8192]: one memset
    float* S    = (float*)(cnt + N);       // strided sums/sumsq, 32KB
    p += align_up((size_t)(N + 8192) * 4);
    int* bucket = (int*)p;   p += align_up((size_t)N * CAP * 4);
    // hsb/g2b have N+1 rows: row N is the zeroed sentinel row
    unsigned short* hsb = (unsigned short*)p; p += align_up((size_t)(N + 1) * D * 2);
    unsigned short* g2b = (unsigned short*)p; p += align_up((size_t)(N + 1) * D * 2);
    unsigned short* h2b = (unsigned short*)p; p += align_up((size_t)N * D * 2);
    unsigned short* Wt1 = (unsigned short*)p; p += align_up((size_t)D * D * 2);
    unsigned short* Wt2 = (unsigned short*)p; p += align_up((size_t)D * D * 2);

    int gemmBlocks = (N + 127) / 128;   // 391
    int fillBlocks = (E + 255) / 256;   // 2344

    hipMemsetAsync(cnt, 0, (size_t)(N + 8192) * 4, stream);
    hipMemsetAsync(hsb + (size_t)N * D, 0, (size_t)D * 2, stream);   // sentinel rows
    hipMemsetAsync(g2b + (size_t)N * D, 0, (size_t)D * 2, stream);
    k_histfill<<<fillBlocks, 256, 0, stream>>>(row, col, cnt, bucket, E,
                                               W1, W2, Wt1, Wt2);
    // layer 1 GEMM (+ bucket sentinel pad)
    k_gemm1<<<gemmBlocks, 1024, 0, stream>>>(x, Wt1, cnt, bucket, hsb, N);
    // fused agg1 + layer 2 GEMM: reads hsb, writes g2b (distinct)
    k_agg_gemm<<<gemmBlocks, 1024, 0, stream>>>((const uint2*)hsb, bucket, cnt, b1,
                                                Wt2, g2b, N);
    // fused layer-2 aggregation + BN stats
    k_agg_stats<<<512, 1024, 0, stream>>>((const uint2*)g2b, bucket, cnt, b2,
                                          h2b, S, N);
    // BN normalize
    k_bn<<<(N * (D / 8) + 255) / 256, 256, 0, stream>>>((const unsigned*)h2b, S,
                                                        gamma, beta, (float*)d_out, N);
}